// Round 6
// baseline (418.022 us; speedup 1.0000x reference)
//
#include <hip/hip_runtime.h>
#include <hip/hip_fp16.h>

// ---------------------------------------------------------------------------
// VariationalGCNEncoder: mu/logstd = GCNConv(relu(GCNConv(x)))
// N=100000, E=1600000, IN=256, HID=128, OUT=64
//
// R6: (a) quad-edge gather: lane = (edge-sub l>>4, chan-slot l&15); one
//     dwordx4 fetches 4 src rows, unroll 4 -> 16 rows in flight/wave,
//     shfl_xor(16,32) reduce. (b) agg2 fused into GEMM2 via swizzled LDS
//     tile (kills 51MB of intermediate traffic + 1 launch).
// Pipeline: bhist->bscan->bpart->bfin | prepacks | gemm1 -> agg<1> -> agg_gemm2
// ---------------------------------------------------------------------------

typedef unsigned short ushort;
typedef __attribute__((ext_vector_type(8))) short bf16x8;
typedef __attribute__((ext_vector_type(8))) _Float16 f16x8;
typedef __attribute__((ext_vector_type(4))) float f32x4;

union U16x8 { uint4 q; ushort u[8]; bf16x8 b; f16x8 h; __half2 hh[4]; };

static __device__ __forceinline__ ushort f2bf(float x) {
    union { float f; unsigned u; } a; a.f = x;
    unsigned r = a.u + 0x7FFFu + ((a.u >> 16) & 1u);  // RNE
    return (ushort)(r >> 16);
}
static __device__ __forceinline__ float bf2f(ushort h) {
    union { unsigned u; float f; } a; a.u = ((unsigned)h) << 16;
    return a.f;
}

#define NBUCK 391  // ceil(100000/256)
#define PCHUNK 4096

// ---------------- bucket histogram -----------------------------------------
__global__ __launch_bounds__(256) void k_bhist(const int* __restrict__ dst,
                                               int* __restrict__ bucketCnt, int E) {
    __shared__ int hist[NBUCK];
    const int t = threadIdx.x;
    const int base = blockIdx.x * PCHUNK;
    const int cnt = min(PCHUNK, E - base);
    for (int i = t; i < NBUCK; i += 256) hist[i] = 0;
    __syncthreads();
    for (int i = t; i < cnt; i += 256) atomicAdd(&hist[dst[base + i] >> 8], 1);
    __syncthreads();
    for (int i = t; i < NBUCK; i += 256)
        if (hist[i]) atomicAdd(&bucketCnt[i], hist[i]);
}

// ---------------- bucket scan (1 block, 512 thr) ---------------------------
__global__ __launch_bounds__(512) void k_bscan(const int* __restrict__ bucketCnt,
                                               int* __restrict__ bucketBase,
                                               int* __restrict__ bucketCursor) {
    __shared__ int sc[512];
    const int t = threadIdx.x;
    sc[t] = (t < NBUCK) ? bucketCnt[t] : 0;
    __syncthreads();
    for (int off = 1; off < 512; off <<= 1) {
        int a = (t >= off) ? sc[t - off] : 0;
        __syncthreads();
        sc[t] += a;
        __syncthreads();
    }
    if (t <= NBUCK) {
        int base = (t == 0) ? 0 : sc[t - 1];
        bucketBase[t] = base;
        if (t < NBUCK) bucketCursor[t] = base;
    }
}

// ---------------- partition: LDS counting sort per 4096-edge chunk ---------
__global__ __launch_bounds__(256) void k_bpart(const int* __restrict__ src,
                                               const int* __restrict__ dst,
                                               int* __restrict__ bucketCursor,
                                               unsigned* __restrict__ cwTmp, int E) {
    __shared__ unsigned words[PCHUNK];
    __shared__ ushort buck[PCHUNK];
    __shared__ unsigned sortedW[PCHUNK];
    __shared__ ushort buck2[PCHUNK];
    __shared__ int sc[512];
    __shared__ int rk[NBUCK];
    __shared__ int runBase[NBUCK];
    const int t = threadIdx.x;
    const int base = blockIdx.x * PCHUNK;
    const int cnt = min(PCHUNK, E - base);

    sc[t] = 0; sc[t + 256] = 0;
    for (int i = t; i < NBUCK; i += 256) rk[i] = 0;
    __syncthreads();
    for (int i = t; i < cnt; i += 256) {
        int s = src[base + i], d = dst[base + i];
        words[i] = ((unsigned)s << 8) | (unsigned)(d & 255);
        int b = d >> 8;
        buck[i] = (ushort)b;
        atomicAdd(&sc[b], 1);
    }
    __syncthreads();
    for (int off = 1; off < 512; off <<= 1) {
        int a0 = (t >= off) ? sc[t - off] : 0;
        int a1 = (t + 256 >= off) ? sc[t + 256 - off] : 0;
        __syncthreads();
        sc[t] += a0;
        sc[t + 256] += a1;
        __syncthreads();
    }
    for (int i = t; i < cnt; i += 256) {
        int b = buck[i];
        int excl = b ? sc[b - 1] : 0;
        int p = excl + atomicAdd(&rk[b], 1);
        sortedW[p] = words[i];
        buck2[p] = (ushort)b;
    }
    __syncthreads();
    for (int b = t; b < NBUCK; b += 256) {
        int len = rk[b];
        if (len > 0) runBase[b] = atomicAdd(&bucketCursor[b], len);
    }
    __syncthreads();
    for (int i = t; i < cnt; i += 256) {
        int b = buck2[i];
        int excl = b ? sc[b - 1] : 0;
        cwTmp[runBase[b] + (i - excl)] = sortedW[i];
    }
}

// ---------------- finalize: per-bucket node sort -> rowptr, dinv, cw -------
__global__ __launch_bounds__(256) void k_bfin(const unsigned* __restrict__ cwTmp,
                                              const int* __restrict__ bucketBase,
                                              int* __restrict__ cw,
                                              int* __restrict__ rowptr,
                                              float* __restrict__ dinv,
                                              int N, int E) {
    __shared__ int hist[256], sc2[256], rk[256];
    const int b = blockIdx.x, t = threadIdx.x;
    const int gbase = bucketBase[b], gend = bucketBase[b + 1];
    const int n0 = b << 8;
    const int nNodes = min(256, N - n0);
    hist[t] = 0;
    rk[t] = 0;
    __syncthreads();
    for (int i = gbase + t; i < gend; i += 256)
        atomicAdd(&hist[cwTmp[i] & 255u], 1);
    __syncthreads();
    sc2[t] = hist[t];
    __syncthreads();
    for (int off = 1; off < 256; off <<= 1) {
        int a = (t >= off) ? sc2[t - off] : 0;
        __syncthreads();
        sc2[t] += a;
        __syncthreads();
    }
    int ex = sc2[t] - hist[t];  // exclusive
    if (t < nNodes) {
        rowptr[n0 + t] = gbase + ex;
        dinv[n0 + t] = rsqrtf((float)hist[t] + 1.0f);  // +1 self-loop
    }
    if (b == 0 && t == 0) rowptr[N] = E;
    __syncthreads();
    for (int i = gbase + t; i < gend; i += 256) {
        unsigned w = cwTmp[i];
        int dL = w & 255u;
        int r = atomicAdd(&rk[dL], 1);
        cw[gbase + (sc2[dL] - hist[dL]) + r] = (int)(w >> 8);
    }
}

// ---------------- weight pre-pack ------------------------------------------
__global__ __launch_bounds__(256) void k_prep_B1(const float* __restrict__ W,
                                                 ushort* __restrict__ hi,
                                                 ushort* __restrict__ lo) {
    int i = blockIdx.x * 256 + threadIdx.x;  // 32*128
    if (i >= 32 * 128) return;
    int kgrp = i >> 7, col = i & 127;
    U16x8 h, l;
#pragma unroll
    for (int j = 0; j < 8; ++j) {
        float x = W[(size_t)(kgrp * 8 + j) * 128 + col];
        h.u[j] = f2bf(x);
        l.u[j] = f2bf(x - bf2f(h.u[j]));
    }
    *(uint4*)(hi + (size_t)i * 8) = h.q;
    *(uint4*)(lo + (size_t)i * 8) = l.q;
}

__global__ __launch_bounds__(256) void k_prep_B2(const float* __restrict__ Wmu,
                                                 const float* __restrict__ Wls,
                                                 ushort* __restrict__ hi,
                                                 ushort* __restrict__ lo) {
    int i = blockIdx.x * 256 + threadIdx.x;  // 16*128
    if (i >= 16 * 128) return;
    int kgrp = i >> 7, col = i & 127;
    U16x8 h, l;
#pragma unroll
    for (int j = 0; j < 8; ++j) {
        int lk = j * 16 + kgrp;  // stored_k -> logical hidden index
        float x = (col < 64) ? Wmu[(size_t)lk * 64 + col]
                             : Wls[(size_t)lk * 64 + col - 64];
        __half hh = __float2half(x);
        __half ll = __float2half(x - __half2float(hh));
        h.u[j] = __half_as_ushort(hh);
        l.u[j] = __half_as_ushort(ll);
    }
    *(uint4*)(hi + (size_t)i * 8) = h.q;
    *(uint4*)(lo + (size_t)i * 8) = l.q;
}

__global__ __launch_bounds__(128) void k_prep_b1(const float* __restrict__ b1,
                                                 float* __restrict__ b1p) {
    int j = threadIdx.x;
    if (j < 128) b1p[j] = b1[(j & 7) * 16 + (j >> 3)];
}

// ---------------- GEMM1: h1' = dinv * (x @ W1), fp16 stored-order ----------
__global__ __launch_bounds__(256) void k_gemm1(const float* __restrict__ A,
                                               const ushort* __restrict__ Bph,
                                               const ushort* __restrict__ Bpl,
                                               const float* __restrict__ dinv,
                                               __half* __restrict__ H1, int M) {
    const int t = threadIdx.x, lane = t & 63;
    const int kgrp = lane >> 4, lrow = lane & 15;
    const int rowBase = blockIdx.x * 128 + (t >> 6) * 32;

    f32x4 acc[2][8];
#pragma unroll
    for (int mf = 0; mf < 2; ++mf)
#pragma unroll
        for (int nf = 0; nf < 8; ++nf) acc[mf][nf] = (f32x4)0.f;

    for (int c = 0; c < 8; ++c) {  // K=256
        bf16x8 ah[2], al[2];
#pragma unroll
        for (int mf = 0; mf < 2; ++mf) {
            int r = rowBase + mf * 16 + lrow;
            if (r >= M) r = M - 1;
            const float* ap = A + (size_t)r * 256 + c * 32 + kgrp * 8;
            float4 x0 = *(const float4*)ap;
            float4 x1 = *(const float4*)(ap + 4);
            float v[8] = {x0.x, x0.y, x0.z, x0.w, x1.x, x1.y, x1.z, x1.w};
            U16x8 h, l;
#pragma unroll
            for (int i = 0; i < 8; ++i) {
                h.u[i] = f2bf(v[i]);
                l.u[i] = f2bf(v[i] - bf2f(h.u[i]));
            }
            ah[mf] = h.b;
            al[mf] = l.b;
        }
#pragma unroll
        for (int nf = 0; nf < 8; ++nf) {
            size_t bo = ((size_t)(c * 4 + kgrp) * 128 + nf * 16 + lrow) * 8;
            U16x8 bh, bl;
            bh.q = *(const uint4*)(Bph + bo);
            bl.q = *(const uint4*)(Bpl + bo);
#pragma unroll
            for (int mf = 0; mf < 2; ++mf) {
                acc[mf][nf] = __builtin_amdgcn_mfma_f32_16x16x32_bf16(
                    ah[mf], bh.b, acc[mf][nf], 0, 0, 0);
                acc[mf][nf] = __builtin_amdgcn_mfma_f32_16x16x32_bf16(
                    ah[mf], bl.b, acc[mf][nf], 0, 0, 0);
                acc[mf][nf] = __builtin_amdgcn_mfma_f32_16x16x32_bf16(
                    al[mf], bh.b, acc[mf][nf], 0, 0, 0);
            }
        }
    }
#pragma unroll
    for (int mf = 0; mf < 2; ++mf)
#pragma unroll
        for (int reg = 0; reg < 4; ++reg) {
            int row = rowBase + mf * 16 + kgrp * 4 + reg;
            if (row < M) {
                float dv = dinv[row];
                union { uint4 q; __half h[8]; } o;
#pragma unroll
                for (int nf = 0; nf < 8; ++nf)
                    o.h[nf] = __float2half(acc[mf][nf][reg] * dv);
                *(uint4*)(H1 + (size_t)row * 128 + lrow * 8) = o.q;
            }
        }
}

// ---------------- quad-edge gather core ------------------------------------
// lane = (sub = l>>4: edge sub-index, lr = l&15: channel slot of 8 ch).
// Accumulates 8 fp32 channels; one dwordx4 load covers 4 src rows per group.
static __device__ __forceinline__ void qacc(float* acc, uint4 q) {
    U16x8 u; u.q = q;
#pragma unroll
    for (int k = 0; k < 4; ++k) {
        float2 f = __half22float2(u.hh[k]);
        acc[2 * k] += f.x;
        acc[2 * k + 1] += f.y;
    }
}

// standalone agg pass 1: hbuf = dinv * relu(dinv*acc + b1p)  (stored order)
__global__ __launch_bounds__(256) void k_agg1(const __half* __restrict__ Hin,
                                              const int* __restrict__ rowptr,
                                              const int* __restrict__ cw,
                                              const float* __restrict__ dinv,
                                              const float* __restrict__ b1p,
                                              __half* __restrict__ Hout, int N) {
    const int node = (blockIdx.x * 256 + threadIdx.x) >> 6;
    if (node >= N) return;
    const int lane = threadIdx.x & 63;
    const int sub = lane >> 4, lr = lane & 15;
    float acc[8] = {0.f, 0.f, 0.f, 0.f, 0.f, 0.f, 0.f, 0.f};
    if (sub == 0) qacc(acc, *(const uint4*)(Hin + (size_t)node * 128 + lr * 8));
    const int start = rowptr[node], end = rowptr[node + 1];
    for (int e = start; e < end; e += 16) {
#pragma unroll
        for (int g = 0; g < 4; ++g) {
            int ee = e + g * 4 + sub;
            if (ee < end) {
                int s = cw[ee];
                qacc(acc, *(const uint4*)(Hin + (size_t)s * 128 + lr * 8));
            }
        }
    }
#pragma unroll
    for (int i = 0; i < 8; ++i) {
        acc[i] += __shfl_xor(acc[i], 16);
        acc[i] += __shfl_xor(acc[i], 32);
    }
    if (sub == 0) {
        float dv = dinv[node];
        float4 b0 = *(const float4*)(b1p + lr * 8);
        float4 b1v = *(const float4*)(b1p + lr * 8 + 4);
        float bb[8] = {b0.x, b0.y, b0.z, b0.w, b1v.x, b1v.y, b1v.z, b1v.w};
        union { uint4 q; __half h[8]; } o;
#pragma unroll
        for (int i = 0; i < 8; ++i)
            o.h[i] = __float2half(fmaxf(fmaf(acc[i], dv, bb[i]), 0.f) * dv);
        *(uint4*)(Hout + (size_t)node * 128 + lr * 8) = o.q;
    }
}

// ---------------- fused agg2 + GEMM2 ---------------------------------------
// Block = 128 nodes. Phase 1: 4 waves x 32 nodes quad-edge gather -> swizzled
// LDS tile (slot ^= row&7). Phase 2: f16 hi/lo MFMA + bias epilogue.
__global__ __launch_bounds__(256) void k_agg_gemm2(
    const __half* __restrict__ Hin, const int* __restrict__ rowptr,
    const int* __restrict__ cw, const float* __restrict__ dinv,
    const ushort* __restrict__ Bph, const ushort* __restrict__ Bpl,
    float* __restrict__ Cmu, float* __restrict__ Cls,
    const float* __restrict__ bmu, const float* __restrict__ bls, int N) {
    __shared__ __align__(16) __half sA[128 * 128];  // 32 KB, 16B-slot swizzled
    const int t = threadIdx.x, lane = t & 63, w = t >> 6;
    const int sub = lane >> 4, lr = lane & 15;
    const int blockRow = blockIdx.x * 128;

    // ---- phase 1: gather 32 nodes per wave
    for (int i = 0; i < 32; ++i) {
        const int rl = w * 32 + i;
        const int node = blockRow + rl;
        const bool nv = node < N;
        float acc[8] = {0.f, 0.f, 0.f, 0.f, 0.f, 0.f, 0.f, 0.f};
        int start = 0, end = 0;
        if (nv) {
            start = rowptr[node];
            end = rowptr[node + 1];
            if (sub == 0)
                qacc(acc, *(const uint4*)(Hin + (size_t)node * 128 + lr * 8));
        }
        for (int e = start; e < end; e += 16) {
#pragma unroll
            for (int g = 0; g < 4; ++g) {
                int ee = e + g * 4 + sub;
                if (ee < end) {
                    int s = cw[ee];
                    qacc(acc, *(const uint4*)(Hin + (size_t)s * 128 + lr * 8));
                }
            }
        }
#pragma unroll
        for (int k = 0; k < 8; ++k) {
            acc[k] += __shfl_xor(acc[k], 16);
            acc[k] += __shfl_xor(acc[k], 32);
        }
        if (sub == 0) {
            float dv = nv ? dinv[node] : 0.f;
            union { uint4 q; __half h[8]; } o;
#pragma unroll
            for (int k = 0; k < 8; ++k) o.h[k] = __float2half(acc[k] * dv);
            int slot = lr ^ (rl & 7);
            *(uint4*)&sA[(size_t)rl * 128 + slot * 8] = o.q;
        }
    }
    __syncthreads();

    // ---- phase 2: MFMA (A from LDS, B hi/lo from global)
    const int kgrp = sub, lrow = lr;
    const int rowBase = w * 32;
    f32x4 acc2[2][8];
#pragma unroll
    for (int mf = 0; mf < 2; ++mf)
#pragma unroll
        for (int nf = 0; nf < 8; ++nf) acc2[mf][nf] = (f32x4)0.f;

    for (int c = 0; c < 4; ++c) {
        f16x8 a[2];
#pragma unroll
        for (int mf = 0; mf < 2; ++mf) {
            int rl = rowBase + mf * 16 + lrow;
            int slot = (c * 4 + kgrp) ^ (rl & 7);
            U16x8 u;
            u.q = *(const uint4*)&sA[(size_t)rl * 128 + slot * 8];
            a[mf] = u.h;
        }
#pragma unroll
        for (int nf = 0; nf < 8; ++nf) {
            size_t bo = ((size_t)(c * 4 + kgrp) * 128 + nf * 16 + lrow) * 8;
            U16x8 bh, bl;
            bh.q = *(const uint4*)(Bph + bo);
            bl.q = *(const uint4*)(Bpl + bo);
#pragma unroll
            for (int mf = 0; mf < 2; ++mf) {
                acc2[mf][nf] = __builtin_amdgcn_mfma_f32_16x16x32_f16(
                    a[mf], bh.h, acc2[mf][nf], 0, 0, 0);
                acc2[mf][nf] = __builtin_amdgcn_mfma_f32_16x16x32_f16(
                    a[mf], bl.h, acc2[mf][nf], 0, 0, 0);
            }
        }
    }
    float bv[8];
#pragma unroll
    for (int nf = 0; nf < 8; ++nf)
        bv[nf] = (nf < 4) ? bmu[nf * 16 + lrow] : bls[(nf - 4) * 16 + lrow];
#pragma unroll
    for (int mf = 0; mf < 2; ++mf)
#pragma unroll
        for (int reg = 0; reg < 4; ++reg) {
            int row = blockRow + rowBase + mf * 16 + kgrp * 4 + reg;
            if (row < N) {
#pragma unroll
                for (int nf = 0; nf < 4; ++nf)
                    Cmu[(size_t)row * 64 + nf * 16 + lrow] = acc2[mf][nf][reg] + bv[nf];
#pragma unroll
                for (int nf = 4; nf < 8; ++nf)
                    Cls[(size_t)row * 64 + (nf - 4) * 16 + lrow] =
                        acc2[mf][nf][reg] + bv[nf];
            }
        }
}

extern "C" void kernel_launch(void* const* d_in, const int* in_sizes, int n_in,
                              void* d_out, int out_size, void* d_ws, size_t ws_size,
                              hipStream_t stream) {
    const float* x   = (const float*)d_in[0];
    const int*   ei  = (const int*)d_in[1];
    const float* W1  = (const float*)d_in[2];
    const float* b1  = (const float*)d_in[3];
    const float* Wmu = (const float*)d_in[4];
    const float* bmu = (const float*)d_in[5];
    const float* Wls = (const float*)d_in[6];
    const float* bls = (const float*)d_in[7];

    const int N = in_sizes[0] / 256;  // 100000
    const int E = in_sizes[1] / 2;    // 1600000
    const int* src = ei;
    const int* dst = ei + E;

    float* out_mu = (float*)d_out;
    float* out_ls = out_mu + (size_t)N * 64;

    // ---- workspace layout ----
    char* wsb = (char*)d_ws;
    const size_t KB = 1024, MB = 1024 * 1024;
    const size_t Hh_BYTES = (size_t)N * 128 * 2;  // 25.6 MB
    int*      bucketCnt    = (int*)(wsb + 0);
    int*      bucketBase   = (int*)(wsb + 4 * KB);
    int*      bucketCursor = (int*)(wsb + 8 * KB);
    float*    b1p          = (float*)(wsb + 16 * KB);
    ushort*   Bp1h         = (ushort*)(wsb + 32 * KB);
    ushort*   Bp1l         = (ushort*)(wsb + 96 * KB);
    ushort*   Bp2h         = (ushort*)(wsb + 160 * KB);
    ushort*   Bp2l         = (ushort*)(wsb + 192 * KB);
    int*      rowptr       = (int*)(wsb + 256 * KB);
    float*    dinv         = (float*)(wsb + 768 * KB);
    unsigned* cwTmp        = (unsigned*)(wsb + 1280 * KB);  // 6.4 MB
    int*      cw           = (int*)(wsb + 8 * MB);          // 6.4 MB
    __half*   h1;   // gemm1 out, agg1 in
    __half*   hbuf; // agg1 out, fused agg2 in (must NOT alias d_out)
    if (ws_size >= 41 * MB + Hh_BYTES) {
        h1   = (__half*)(wsb + 15 * MB);
        hbuf = (__half*)(wsb + 41 * MB);
    } else {
        h1   = (__half*)d_out;  // 25.6 <= 51.2 MB; dead before fused GEMM2 writes
        hbuf = (__half*)(wsb + 15 * MB);
    }

    const int nChunks  = (E + PCHUNK - 1) / PCHUNK;  // 391
    const int nBlkAgg  = (N + 3) / 4;
    const int nBlkGemm = (N + 127) / 128;

    // ---- CSR build (bucketed counting sort) ----
    hipMemsetAsync(bucketCnt, 0, 392 * 4, stream);
    k_bhist<<<nChunks, 256, 0, stream>>>(dst, bucketCnt, E);
    k_bscan<<<1, 512, 0, stream>>>(bucketCnt, bucketBase, bucketCursor);
    k_bpart<<<nChunks, 256, 0, stream>>>(src, dst, bucketCursor, cwTmp, E);
    k_bfin<<<NBUCK, 256, 0, stream>>>(cwTmp, bucketBase, cw, rowptr, dinv, N, E);

    // ---- weight prepacks ----
    k_prep_B1<<<16, 256, 0, stream>>>(W1, Bp1h, Bp1l);
    k_prep_B2<<<8, 256, 0, stream>>>(Wmu, Wls, Bp2h, Bp2l);
    k_prep_b1<<<1, 128, 0, stream>>>(b1, b1p);

    // ---- layer 1 ----
    k_gemm1<<<nBlkGemm, 256, 0, stream>>>(x, Bp1h, Bp1l, dinv, h1, N);
    k_agg1<<<nBlkAgg, 256, 0, stream>>>(h1, rowptr, cw, dinv, b1p, hbuf, N);

    // ---- layer 2 (fused agg + GEMM2) ----
    k_agg_gemm2<<<nBlkGemm, 256, 0, stream>>>(hbuf, rowptr, cw, dinv, Bp2h, Bp2l,
                                              out_mu, out_ls, bmu, bls, N);
}

// Round 7
// 265.686 us; speedup vs baseline: 1.5734x; 1.5734x over previous
//
#include <hip/hip_runtime.h>
#include <hip/hip_fp16.h>

// ---------------------------------------------------------------------------
// VariationalGCNEncoder: mu/logstd = GCNConv(relu(GCNConv(x)))
// N=100000, E=1600000, IN=256, HID=128, OUT=64
//
// R7: revert R6 fusion (it starved the gather of TLP: 242us vs 66+18).
//     R5 pipeline + bpart PCHUNK 2048 (5 blk/CU vs 3), merged prepack
//     launch, nontemporal final stores.
// Pipeline: bhist->bscan->bpart->bfin | prep_all | gemm1 -> agg<1> -> agg<0>
//           -> gemm2
// ---------------------------------------------------------------------------

typedef unsigned short ushort;
typedef __attribute__((ext_vector_type(8))) short bf16x8;
typedef __attribute__((ext_vector_type(8))) _Float16 f16x8;
typedef __attribute__((ext_vector_type(4))) float f32x4;

union U16x8 { uint4 q; ushort u[8]; bf16x8 b; f16x8 h; __half2 hh[4]; };

static __device__ __forceinline__ ushort f2bf(float x) {
    union { float f; unsigned u; } a; a.f = x;
    unsigned r = a.u + 0x7FFFu + ((a.u >> 16) & 1u);  // RNE
    return (ushort)(r >> 16);
}
static __device__ __forceinline__ float bf2f(ushort h) {
    union { unsigned u; float f; } a; a.u = ((unsigned)h) << 16;
    return a.f;
}

#define NBUCK 391   // ceil(100000/256)
#define BH_CHUNK 4096
#define BP_CHUNK 2048

// ---------------- bucket histogram -----------------------------------------
__global__ __launch_bounds__(256) void k_bhist(const int* __restrict__ dst,
                                               int* __restrict__ bucketCnt, int E) {
    __shared__ int hist[NBUCK];
    const int t = threadIdx.x;
    const int base = blockIdx.x * BH_CHUNK;
    const int cnt = min(BH_CHUNK, E - base);
    for (int i = t; i < NBUCK; i += 256) hist[i] = 0;
    __syncthreads();
    for (int i = t; i < cnt; i += 256) atomicAdd(&hist[dst[base + i] >> 8], 1);
    __syncthreads();
    for (int i = t; i < NBUCK; i += 256)
        if (hist[i]) atomicAdd(&bucketCnt[i], hist[i]);
}

// ---------------- bucket scan (1 block, 512 thr) ---------------------------
__global__ __launch_bounds__(512) void k_bscan(const int* __restrict__ bucketCnt,
                                               int* __restrict__ bucketBase,
                                               int* __restrict__ bucketCursor) {
    __shared__ int sc[512];
    const int t = threadIdx.x;
    sc[t] = (t < NBUCK) ? bucketCnt[t] : 0;
    __syncthreads();
    for (int off = 1; off < 512; off <<= 1) {
        int a = (t >= off) ? sc[t - off] : 0;
        __syncthreads();
        sc[t] += a;
        __syncthreads();
    }
    if (t <= NBUCK) {
        int base = (t == 0) ? 0 : sc[t - 1];
        bucketBase[t] = base;
        if (t < NBUCK) bucketCursor[t] = base;
    }
}

// ---------------- partition: LDS counting sort per 2048-edge chunk ---------
__global__ __launch_bounds__(256) void k_bpart(const int* __restrict__ src,
                                               const int* __restrict__ dst,
                                               int* __restrict__ bucketCursor,
                                               unsigned* __restrict__ cwTmp, int E) {
    __shared__ unsigned words[BP_CHUNK];
    __shared__ ushort buck[BP_CHUNK];
    __shared__ unsigned sortedW[BP_CHUNK];
    __shared__ ushort buck2[BP_CHUNK];
    __shared__ int sc[512];
    __shared__ int rk[NBUCK];
    __shared__ int runBase[NBUCK];
    const int t = threadIdx.x;
    const int base = blockIdx.x * BP_CHUNK;
    const int cnt = min(BP_CHUNK, E - base);

    sc[t] = 0; sc[t + 256] = 0;
    for (int i = t; i < NBUCK; i += 256) rk[i] = 0;
    __syncthreads();
    for (int i = t; i < cnt; i += 256) {
        int s = src[base + i], d = dst[base + i];
        words[i] = ((unsigned)s << 8) | (unsigned)(d & 255);
        int b = d >> 8;
        buck[i] = (ushort)b;
        atomicAdd(&sc[b], 1);
    }
    __syncthreads();
    for (int off = 1; off < 512; off <<= 1) {
        int a0 = (t >= off) ? sc[t - off] : 0;
        int a1 = (t + 256 >= off) ? sc[t + 256 - off] : 0;
        __syncthreads();
        sc[t] += a0;
        sc[t + 256] += a1;
        __syncthreads();
    }
    for (int i = t; i < cnt; i += 256) {
        int b = buck[i];
        int excl = b ? sc[b - 1] : 0;
        int p = excl + atomicAdd(&rk[b], 1);
        sortedW[p] = words[i];
        buck2[p] = (ushort)b;
    }
    __syncthreads();
    for (int b = t; b < NBUCK; b += 256) {
        int len = rk[b];
        if (len > 0) runBase[b] = atomicAdd(&bucketCursor[b], len);
    }
    __syncthreads();
    for (int i = t; i < cnt; i += 256) {
        int b = buck2[i];
        int excl = b ? sc[b - 1] : 0;
        cwTmp[runBase[b] + (i - excl)] = sortedW[i];
    }
}

// ---------------- finalize: per-bucket node sort -> rowptr, dinv, cw -------
__global__ __launch_bounds__(256) void k_bfin(const unsigned* __restrict__ cwTmp,
                                              const int* __restrict__ bucketBase,
                                              int* __restrict__ cw,
                                              int* __restrict__ rowptr,
                                              float* __restrict__ dinv,
                                              int N, int E) {
    __shared__ int hist[256], sc2[256], rk[256];
    const int b = blockIdx.x, t = threadIdx.x;
    const int gbase = bucketBase[b], gend = bucketBase[b + 1];
    const int n0 = b << 8;
    const int nNodes = min(256, N - n0);
    hist[t] = 0;
    rk[t] = 0;
    __syncthreads();
    for (int i = gbase + t; i < gend; i += 256)
        atomicAdd(&hist[cwTmp[i] & 255u], 1);
    __syncthreads();
    sc2[t] = hist[t];
    __syncthreads();
    for (int off = 1; off < 256; off <<= 1) {
        int a = (t >= off) ? sc2[t - off] : 0;
        __syncthreads();
        sc2[t] += a;
        __syncthreads();
    }
    int ex = sc2[t] - hist[t];  // exclusive
    if (t < nNodes) {
        rowptr[n0 + t] = gbase + ex;
        dinv[n0 + t] = rsqrtf((float)hist[t] + 1.0f);  // +1 self-loop
    }
    if (b == 0 && t == 0) rowptr[N] = E;
    __syncthreads();
    for (int i = gbase + t; i < gend; i += 256) {
        unsigned w = cwTmp[i];
        int dL = w & 255u;
        int r = atomicAdd(&rk[dL], 1);
        cw[gbase + (sc2[dL] - hist[dL]) + r] = (int)(w >> 8);
    }
}

// ---------------- merged weight pre-pack (25 blocks) -----------------------
// blocks 0..15: B1 (bf16 hi/lo, [kgrp][col][kin], logical k)
// blocks 16..23: B2 ([Wmu|Wls] f16 hi/lo, K-rows permuted: lk = j*16+kgrp)
// block 24: b1p[j] = b1[(j&7)*16 + (j>>3)]
__global__ __launch_bounds__(256) void k_prep_all(
    const float* __restrict__ W1, const float* __restrict__ Wmu,
    const float* __restrict__ Wls, const float* __restrict__ b1,
    ushort* __restrict__ B1h, ushort* __restrict__ B1l,
    ushort* __restrict__ B2h, ushort* __restrict__ B2l,
    float* __restrict__ b1p) {
    const int b = blockIdx.x, t = threadIdx.x;
    if (b < 16) {
        int i = b * 256 + t;  // 32*128 entries
        int kgrp = i >> 7, col = i & 127;
        U16x8 h, l;
#pragma unroll
        for (int j = 0; j < 8; ++j) {
            float x = W1[(size_t)(kgrp * 8 + j) * 128 + col];
            h.u[j] = f2bf(x);
            l.u[j] = f2bf(x - bf2f(h.u[j]));
        }
        *(uint4*)(B1h + (size_t)i * 8) = h.q;
        *(uint4*)(B1l + (size_t)i * 8) = l.q;
    } else if (b < 24) {
        int i = (b - 16) * 256 + t;  // 16*128 entries
        int kgrp = i >> 7, col = i & 127;
        U16x8 h, l;
#pragma unroll
        for (int j = 0; j < 8; ++j) {
            int lk = j * 16 + kgrp;  // stored_k -> logical hidden index
            float x = (col < 64) ? Wmu[(size_t)lk * 64 + col]
                                 : Wls[(size_t)lk * 64 + col - 64];
            __half hh = __float2half(x);
            __half ll = __float2half(x - __half2float(hh));
            h.u[j] = __half_as_ushort(hh);
            l.u[j] = __half_as_ushort(ll);
        }
        *(uint4*)(B2h + (size_t)i * 8) = h.q;
        *(uint4*)(B2l + (size_t)i * 8) = l.q;
    } else {
        if (t < 128) b1p[t] = b1[(t & 7) * 16 + (t >> 3)];
    }
}

// ---------------- GEMM1: h1' = dinv * (x @ W1), fp16 stored-order ----------
__global__ __launch_bounds__(256) void k_gemm1(const float* __restrict__ A,
                                               const ushort* __restrict__ Bph,
                                               const ushort* __restrict__ Bpl,
                                               const float* __restrict__ dinv,
                                               __half* __restrict__ H1, int M) {
    const int t = threadIdx.x, lane = t & 63;
    const int kgrp = lane >> 4, lrow = lane & 15;
    const int rowBase = blockIdx.x * 128 + (t >> 6) * 32;

    f32x4 acc[2][8];
#pragma unroll
    for (int mf = 0; mf < 2; ++mf)
#pragma unroll
        for (int nf = 0; nf < 8; ++nf) acc[mf][nf] = (f32x4)0.f;

    for (int c = 0; c < 8; ++c) {  // K=256
        bf16x8 ah[2], al[2];
#pragma unroll
        for (int mf = 0; mf < 2; ++mf) {
            int r = rowBase + mf * 16 + lrow;
            if (r >= M) r = M - 1;
            const float* ap = A + (size_t)r * 256 + c * 32 + kgrp * 8;
            float4 x0 = *(const float4*)ap;
            float4 x1 = *(const float4*)(ap + 4);
            float v[8] = {x0.x, x0.y, x0.z, x0.w, x1.x, x1.y, x1.z, x1.w};
            U16x8 h, l;
#pragma unroll
            for (int i = 0; i < 8; ++i) {
                h.u[i] = f2bf(v[i]);
                l.u[i] = f2bf(v[i] - bf2f(h.u[i]));
            }
            ah[mf] = h.b;
            al[mf] = l.b;
        }
#pragma unroll
        for (int nf = 0; nf < 8; ++nf) {
            size_t bo = ((size_t)(c * 4 + kgrp) * 128 + nf * 16 + lrow) * 8;
            U16x8 bh, bl;
            bh.q = *(const uint4*)(Bph + bo);
            bl.q = *(const uint4*)(Bpl + bo);
#pragma unroll
            for (int mf = 0; mf < 2; ++mf) {
                acc[mf][nf] = __builtin_amdgcn_mfma_f32_16x16x32_bf16(
                    ah[mf], bh.b, acc[mf][nf], 0, 0, 0);
                acc[mf][nf] = __builtin_amdgcn_mfma_f32_16x16x32_bf16(
                    ah[mf], bl.b, acc[mf][nf], 0, 0, 0);
                acc[mf][nf] = __builtin_amdgcn_mfma_f32_16x16x32_bf16(
                    al[mf], bh.b, acc[mf][nf], 0, 0, 0);
            }
        }
    }
#pragma unroll
    for (int mf = 0; mf < 2; ++mf)
#pragma unroll
        for (int reg = 0; reg < 4; ++reg) {
            int row = rowBase + mf * 16 + kgrp * 4 + reg;
            if (row < M) {
                float dv = dinv[row];
                union { uint4 q; __half h[8]; } o;
#pragma unroll
                for (int nf = 0; nf < 8; ++nf)
                    o.h[nf] = __float2half(acc[mf][nf][reg] * dv);
                *(uint4*)(H1 + (size_t)row * 128 + lrow * 8) = o.q;
            }
        }
}

// ---------------- CSR gather (pure adds; rows pre-scaled) ------------------
// EPI==1: out = dinv * relu(dinv*acc + b1p)   (stored order)
// EPI==0: out = dinv * acc                    (true agg2, GEMM2 input)
template <int EPI>
__global__ __launch_bounds__(256) void k_agg(const __half* __restrict__ Hin,
                                             const int* __restrict__ rowptr,
                                             const int* __restrict__ cw,
                                             const float* __restrict__ dinv,
                                             const float* __restrict__ b1p,
                                             __half* __restrict__ Hout, int N) {
    int node = (blockIdx.x * 256 + threadIdx.x) >> 6;
    int lane = threadIdx.x & 63;
    if (node >= N) return;
    float2 acc = __half22float2(((const __half2*)(Hin + (size_t)node * 128))[lane]);
    int e = rowptr[node], end = rowptr[node + 1];
    for (; e + 8 <= end; e += 8) {
        int s0 = cw[e], s1 = cw[e + 1], s2 = cw[e + 2], s3 = cw[e + 3];
        int s4 = cw[e + 4], s5 = cw[e + 5], s6 = cw[e + 6], s7 = cw[e + 7];
        float2 f0 = __half22float2(((const __half2*)(Hin + (size_t)s0 * 128))[lane]);
        float2 f1 = __half22float2(((const __half2*)(Hin + (size_t)s1 * 128))[lane]);
        float2 f2 = __half22float2(((const __half2*)(Hin + (size_t)s2 * 128))[lane]);
        float2 f3 = __half22float2(((const __half2*)(Hin + (size_t)s3 * 128))[lane]);
        float2 f4 = __half22float2(((const __half2*)(Hin + (size_t)s4 * 128))[lane]);
        float2 f5 = __half22float2(((const __half2*)(Hin + (size_t)s5 * 128))[lane]);
        float2 f6 = __half22float2(((const __half2*)(Hin + (size_t)s6 * 128))[lane]);
        float2 f7 = __half22float2(((const __half2*)(Hin + (size_t)s7 * 128))[lane]);
        acc.x += f0.x; acc.y += f0.y; acc.x += f1.x; acc.y += f1.y;
        acc.x += f2.x; acc.y += f2.y; acc.x += f3.x; acc.y += f3.y;
        acc.x += f4.x; acc.y += f4.y; acc.x += f5.x; acc.y += f5.y;
        acc.x += f6.x; acc.y += f6.y; acc.x += f7.x; acc.y += f7.y;
    }
    for (; e + 2 <= end; e += 2) {
        int s0 = cw[e], s1 = cw[e + 1];
        float2 f0 = __half22float2(((const __half2*)(Hin + (size_t)s0 * 128))[lane]);
        float2 f1 = __half22float2(((const __half2*)(Hin + (size_t)s1 * 128))[lane]);
        acc.x += f0.x; acc.y += f0.y; acc.x += f1.x; acc.y += f1.y;
    }
    if (e < end) {
        int s0 = cw[e];
        float2 f0 = __half22float2(((const __half2*)(Hin + (size_t)s0 * 128))[lane]);
        acc.x += f0.x; acc.y += f0.y;
    }
    float dv = dinv[node];
    if (EPI == 1) {
        float2 bb = ((const float2*)b1p)[lane];
        acc.x = fmaxf(fmaf(acc.x, dv, bb.x), 0.f) * dv;
        acc.y = fmaxf(fmaf(acc.y, dv, bb.y), 0.f) * dv;
    } else {
        acc.x *= dv;
        acc.y *= dv;
    }
    ((__half2*)(Hout + (size_t)node * 128))[lane] = __float22half2_rn(acc);
}

// ---------------- GEMM2: [mu|ls] = agg2 @ [Wmu|Wls] + bias -----------------
__global__ __launch_bounds__(256) void k_gemm2(const __half* __restrict__ A,
                                               const ushort* __restrict__ Bph,
                                               const ushort* __restrict__ Bpl,
                                               float* __restrict__ Cmu,
                                               float* __restrict__ Cls,
                                               const float* __restrict__ bmu,
                                               const float* __restrict__ bls, int M) {
    const int t = threadIdx.x, lane = t & 63;
    const int kgrp = lane >> 4, lrow = lane & 15;
    const int rowBase = blockIdx.x * 128 + (t >> 6) * 32;

    f32x4 acc[2][8];
#pragma unroll
    for (int mf = 0; mf < 2; ++mf)
#pragma unroll
        for (int nf = 0; nf < 8; ++nf) acc[mf][nf] = (f32x4)0.f;

    for (int c = 0; c < 4; ++c) {  // K=128 stored
        f16x8 a[2];
#pragma unroll
        for (int mf = 0; mf < 2; ++mf) {
            int r = rowBase + mf * 16 + lrow;
            if (r >= M) r = M - 1;
            U16x8 u;
            u.q = *(const uint4*)(A + (size_t)r * 128 + c * 32 + kgrp * 8);
            a[mf] = u.h;
        }
#pragma unroll
        for (int nf = 0; nf < 8; ++nf) {
            size_t bo = ((size_t)(c * 4 + kgrp) * 128 + nf * 16 + lrow) * 8;
            U16x8 bh, bl;
            bh.q = *(const uint4*)(Bph + bo);
            bl.q = *(const uint4*)(Bpl + bo);
#pragma unroll
            for (int mf = 0; mf < 2; ++mf) {
                acc[mf][nf] = __builtin_amdgcn_mfma_f32_16x16x32_f16(
                    a[mf], bh.h, acc[mf][nf], 0, 0, 0);
                acc[mf][nf] = __builtin_amdgcn_mfma_f32_16x16x32_f16(
                    a[mf], bl.h, acc[mf][nf], 0, 0, 0);
            }
        }
    }
    float bv[8];
#pragma unroll
    for (int nf = 0; nf < 8; ++nf)
        bv[nf] = (nf < 4) ? bmu[nf * 16 + lrow] : bls[(nf - 4) * 16 + lrow];
#pragma unroll
    for (int mf = 0; mf < 2; ++mf)
#pragma unroll
        for (int reg = 0; reg < 4; ++reg) {
            int row = rowBase + mf * 16 + kgrp * 4 + reg;
            if (row < M) {
#pragma unroll
                for (int nf = 0; nf < 4; ++nf)
                    __builtin_nontemporal_store(
                        acc[mf][nf][reg] + bv[nf],
                        &Cmu[(size_t)row * 64 + nf * 16 + lrow]);
#pragma unroll
                for (int nf = 4; nf < 8; ++nf)
                    __builtin_nontemporal_store(
                        acc[mf][nf][reg] + bv[nf],
                        &Cls[(size_t)row * 64 + (nf - 4) * 16 + lrow]);
            }
        }
}

extern "C" void kernel_launch(void* const* d_in, const int* in_sizes, int n_in,
                              void* d_out, int out_size, void* d_ws, size_t ws_size,
                              hipStream_t stream) {
    const float* x   = (const float*)d_in[0];
    const int*   ei  = (const int*)d_in[1];
    const float* W1  = (const float*)d_in[2];
    const float* b1  = (const float*)d_in[3];
    const float* Wmu = (const float*)d_in[4];
    const float* bmu = (const float*)d_in[5];
    const float* Wls = (const float*)d_in[6];
    const float* bls = (const float*)d_in[7];

    const int N = in_sizes[0] / 256;  // 100000
    const int E = in_sizes[1] / 2;    // 1600000
    const int* src = ei;
    const int* dst = ei + E;

    float* out_mu = (float*)d_out;
    float* out_ls = out_mu + (size_t)N * 64;

    // ---- workspace layout ----
    char* wsb = (char*)d_ws;
    const size_t KB = 1024, MB = 1024 * 1024;
    const size_t Hh_BYTES = (size_t)N * 128 * 2;  // 25.6 MB
    int*      bucketCnt    = (int*)(wsb + 0);
    int*      bucketBase   = (int*)(wsb + 4 * KB);
    int*      bucketCursor = (int*)(wsb + 8 * KB);
    float*    b1p          = (float*)(wsb + 16 * KB);
    ushort*   Bp1h         = (ushort*)(wsb + 32 * KB);
    ushort*   Bp1l         = (ushort*)(wsb + 96 * KB);
    ushort*   Bp2h         = (ushort*)(wsb + 160 * KB);
    ushort*   Bp2l         = (ushort*)(wsb + 192 * KB);
    int*      rowptr       = (int*)(wsb + 256 * KB);
    float*    dinv         = (float*)(wsb + 768 * KB);
    unsigned* cwTmp        = (unsigned*)(wsb + 1280 * KB);  // 6.4 MB
    int*      cw           = (int*)(wsb + 8 * MB);          // 6.4 MB
    __half*   h1           = (__half*)(wsb + 15 * MB);      // 25.6 MB
    __half*   hbuf;                                         // h'
    __half*   agg2;
    if (ws_size >= 67 * MB + Hh_BYTES) {
        hbuf = (__half*)(wsb + 41 * MB);
        agg2 = (__half*)(wsb + 67 * MB);
    } else {
        hbuf = (__half*)d_out;  // 25.6 <= 51.2 MB; d_out rewritten by GEMM2
        agg2 = (__half*)(wsb + 41 * MB);
    }

    const int nChunksH = (E + BH_CHUNK - 1) / BH_CHUNK;  // 391
    const int nChunksP = (E + BP_CHUNK - 1) / BP_CHUNK;  // 782
    const int nBlkAgg  = (N + 3) / 4;
    const int nBlkGemm = (N + 127) / 128;

    // ---- CSR build (bucketed counting sort) ----
    hipMemsetAsync(bucketCnt, 0, 392 * 4, stream);
    k_bhist<<<nChunksH, 256, 0, stream>>>(dst, bucketCnt, E);
    k_bscan<<<1, 512, 0, stream>>>(bucketCnt, bucketBase, bucketCursor);
    k_bpart<<<nChunksP, 256, 0, stream>>>(src, dst, bucketCursor, cwTmp, E);
    k_bfin<<<NBUCK, 256, 0, stream>>>(cwTmp, bucketBase, cw, rowptr, dinv, N, E);

    // ---- weight prepacks (single launch) ----
    k_prep_all<<<25, 256, 0, stream>>>(W1, Wmu, Wls, b1, Bp1h, Bp1l, Bp2h, Bp2l, b1p);

    // ---- layer 1 ----
    k_gemm1<<<nBlkGemm, 256, 0, stream>>>(x, Bp1h, Bp1l, dinv, h1, N);
    k_agg<1><<<nBlkAgg, 256, 0, stream>>>(h1, rowptr, cw, dinv, b1p, hbuf, N);

    // ---- layer 2 ----
    k_agg<0><<<nBlkAgg, 256, 0, stream>>>(hbuf, rowptr, cw, dinv, nullptr, agg2, N);
    k_gemm2<<<nBlkGemm, 256, 0, stream>>>(agg2, Bp2h, Bp2l, out_mu, out_ls,
                                          bmu, bls, N);
}